// Round 14
// baseline (957.650 us; speedup 1.0000x reference)
//
#include <hip/hip_runtime.h>

#define L_SEQ 2304
#define HID_D 3072
#define NH_D 24
#define HD_D 128
#define N1_D 21504   // 3*HID + MLP
#define QKVN 9216    // 3*HID
#define K2_D 15360   // HID + MLP
#define EPS_V 1e-6f
#define ATTN_SC 0.08838834764831843f  // 1/sqrt(128)

typedef __bf16 bf16x8 __attribute__((ext_vector_type(8)));
typedef float f32x4 __attribute__((ext_vector_type(4)));
typedef unsigned int u32x4 __attribute__((ext_vector_type(4)));
typedef unsigned short u16x8 __attribute__((ext_vector_type(8)));
typedef unsigned short u16x4 __attribute__((ext_vector_type(4)));

#define WAITVM(N) asm volatile("s_waitcnt vmcnt(" #N ")" ::: "memory")
#define LGKM0 asm volatile("s_waitcnt lgkmcnt(0)" ::: "memory")
#define SB0 __builtin_amdgcn_sched_barrier(0)

__device__ __forceinline__ unsigned short f2bf(float f) {
  unsigned int u = __builtin_bit_cast(unsigned int, f);
  u += 0x7fffu + ((u >> 16) & 1u);   // round-to-nearest-even
  return (unsigned short)(u >> 16);
}
__device__ __forceinline__ float bf2f(unsigned short u) {
  return __builtin_bit_cast(float, (unsigned int)u << 16);
}

__device__ __forceinline__ float gelu_f(float x) {
  float u = 0.7978845608028654f * (x + 0.044715f * x * x * x);
  float e = __expf(2.f * u);
  float th = 1.f - 2.f / (e + 1.f);   // tanh(u), overflow-safe
  return 0.5f * x * (1.f + th);
}

// async global->LDS, 16B per lane; lds base must be wave-uniform
__device__ __forceinline__ void gload16(const void* g, void* l) {
  __builtin_amdgcn_global_load_lds(
      (const __attribute__((address_space(1))) unsigned int*)g,
      (__attribute__((address_space(3))) unsigned int*)l, 16, 0, 0);
}

// ---------------- mod = silu(vec) @ mod_w + mod_b ----------------
__global__ __launch_bounds__(256) void mod_partial_kernel(
    const float* __restrict__ vec, const float* __restrict__ mod_w,
    float* __restrict__ partial) {
  __shared__ float s[384];
  const int t = threadIdx.x;
  const int kb = blockIdx.y;
  const int k0 = kb * 384;
  for (int p = t; p < 384; p += 256) {
    float v = vec[k0 + p];
    s[p] = v / (1.f + __expf(-v));
  }
  __syncthreads();
  const int n = blockIdx.x * 256 + t;
  float acc = 0.f;
  const float* wp = mod_w + (size_t)k0 * QKVN + n;
#pragma unroll 4
  for (int j = 0; j < 384; ++j) acc += s[j] * wp[(size_t)j * QKVN];
  partial[kb * QKVN + n] = acc;
}

__global__ __launch_bounds__(256) void mod_reduce_kernel(
    const float* __restrict__ partial, const float* __restrict__ mod_b,
    float* __restrict__ mod) {
  const int n = blockIdx.x * 256 + threadIdx.x;
  float acc = mod_b[n];
#pragma unroll
  for (int i = 0; i < 8; ++i) acc += partial[i * QKVN + n];
  mod[n] = acc;
}

// ---------------- x_mod = LN(x)*(1+scale) + shift  (bf16) ----------------
__global__ __launch_bounds__(256) void ln_mod_kernel(
    const float* __restrict__ x, const float* __restrict__ mod,
    unsigned short* __restrict__ xmod) {
  const int row = blockIdx.x;
  const int t = threadIdx.x;
  const float* xr = x + (size_t)row * HID_D;
  float4 v[3];
  float sum = 0.f, sq = 0.f;
#pragma unroll
  for (int p = 0; p < 3; ++p) {
    v[p] = *(const float4*)&xr[p * 1024 + t * 4];
    sum += v[p].x + v[p].y + v[p].z + v[p].w;
    sq += v[p].x * v[p].x + v[p].y * v[p].y + v[p].z * v[p].z + v[p].w * v[p].w;
  }
#pragma unroll
  for (int o = 1; o < 64; o <<= 1) {
    sum += __shfl_xor(sum, o);
    sq += __shfl_xor(sq, o);
  }
  __shared__ float rs[8];
  const int w = t >> 6;
  if ((t & 63) == 0) { rs[w] = sum; rs[4 + w] = sq; }
  __syncthreads();
  sum = rs[0] + rs[1] + rs[2] + rs[3];
  sq = rs[4] + rs[5] + rs[6] + rs[7];
  const float mu = sum * (1.f / HID_D);
  const float var = sq * (1.f / HID_D) - mu * mu;
  const float rstd = rsqrtf(var + EPS_V);
#pragma unroll
  for (int p = 0; p < 3; ++p) {
    const int c = p * 1024 + t * 4;
    float4 sc = *(const float4*)&mod[3072 + c];
    float4 sh = *(const float4*)&mod[c];
    u16x4 o4;
    o4[0] = f2bf((v[p].x - mu) * rstd * (1.f + sc.x) + sh.x);
    o4[1] = f2bf((v[p].y - mu) * rstd * (1.f + sc.y) + sh.y);
    o4[2] = f2bf((v[p].z - mu) * rstd * (1.f + sc.z) + sh.z);
    o4[3] = f2bf((v[p].w - mu) * rstd * (1.f + sc.w) + sh.w);
    *(u16x4*)&xmod[(size_t)row * HID_D + c] = o4;
  }
}

// ---------------- convert+transpose: src f32 [K][N] -> dst bf16 [N][K] ----------------
__global__ __launch_bounds__(256) void convert_transpose_kernel(
    const float* __restrict__ src, unsigned short* __restrict__ dst,
    const int K, const int N) {
  __shared__ unsigned short lt[64][72];
  const int t = threadIdx.x;
  const int n0 = blockIdx.x * 64;
  const int k0 = blockIdx.y * 64;
  const int kr = t >> 4;
  const int n4 = (t & 15) * 4;
#pragma unroll
  for (int p = 0; p < 4; ++p) {
    const int k = kr + p * 16;
    float4 v = *(const float4*)&src[(size_t)(k0 + k) * N + n0 + n4];
    lt[n4 + 0][k] = f2bf(v.x);
    lt[n4 + 1][k] = f2bf(v.y);
    lt[n4 + 2][k] = f2bf(v.z);
    lt[n4 + 3][k] = f2bf(v.w);
  }
  __syncthreads();
  const int nr = t >> 2;
  const int kc = (t & 3) * 16;
  u16x8 a = *(const u16x8*)&lt[nr][kc];
  u16x8 b = *(const u16x8*)&lt[nr][kc + 8];
  unsigned short* dp = &dst[(size_t)(n0 + nr) * K + k0 + kc];
  *(u16x8*)dp = a;
  *(u16x8*)(dp + 8) = b;
}

// ======== 8-phase deep-pipelined GEMM core (R7, proven; both GEMMs) ========
template <int BM>
__device__ __forceinline__ void gemm8_core(
    const unsigned short* __restrict__ A, const int lda,
    const unsigned short* __restrict__ B, const int ldb,
    const int m0, const int n0, const int nit, char* lds, f32x4 (*acc)[4]) {
  constexpr int AREG = (BM == 256) ? 16384 : 8192;
  constexpr int ABUF = 2 * AREG;
  constexpr int BOFF = 2 * ABUF;
  constexpr int BREG = 16384;
  constexpr int BBUF = 32768;
  constexpr int AROWS = (BM == 256) ? 128 : 64;
  constexpr int AI = (BM == 256) ? 2 : 1;
  constexpr int MF = (BM == 256) ? 4 : 2;
  constexpr int QM = (BM == 256) ? 64 : 32;

  const int t = threadIdx.x;
  const int lane = t & 63;
  const int w = t >> 6;
  const int g = lane >> 4;
  const int c = lane & 15;
  const int sr8 = lane >> 3;
  const int scol = ((lane & 7) ^ sr8) * 8;
  const int arg = w >> 2;
  const int brg = (w & 3) >> 1;
  const int bbase = (w & 1) * 64;

  auto stageA = [&](int buf, int rg, int kt) {
#pragma unroll
    for (int i = 0; i < AI; ++i)
      gload16(A + (size_t)(m0 + rg * AROWS + i * 64 + w * 8 + sr8) * lda +
                  kt * 64 + scol,
              lds + buf * ABUF + rg * AREG + i * 8192 + w * 1024);
  };
  auto stageB = [&](int buf, int rg, int kt) {
#pragma unroll
    for (int i = 0; i < 2; ++i)
      gload16(B + (size_t)(n0 + rg * 128 + i * 64 + w * 8 + sr8) * ldb +
                  kt * 64 + scol,
              lds + BOFF + buf * BBUF + rg * BREG + i * 8192 + w * 1024);
  };

  bf16x8 af[2 * MF], bq0[4], bq1[4];
  auto ldA = [&](int buf, int qm) {
    const char* ab = lds + buf * ABUF + arg * AREG;
#pragma unroll
    for (int i = 0; i < MF; ++i) {
      const int lr = qm * QM + i * 16 + c;
#pragma unroll
      for (int kk = 0; kk < 2; ++kk)
        af[i * 2 + kk] =
            *(const bf16x8*)(ab + lr * 128 + (((kk * 4 + g) ^ (c & 7)) << 4));
    }
  };
  auto ldB = [&](int buf, int qn, bf16x8* bq) {
    const char* bb = lds + BOFF + buf * BBUF + brg * BREG;
#pragma unroll
    for (int i = 0; i < 2; ++i) {
      const int lr = bbase + qn * 32 + i * 16 + c;
#pragma unroll
      for (int kk = 0; kk < 2; ++kk)
        bq[i * 2 + kk] =
            *(const bf16x8*)(bb + lr * 128 + (((kk * 4 + g) ^ (c & 7)) << 4));
    }
  };
  auto domf = [&](int qm, int qn, const bf16x8* bq) {
#pragma unroll
    for (int i = 0; i < MF; ++i)
#pragma unroll
      for (int n = 0; n < 2; ++n)
#pragma unroll
        for (int kk = 0; kk < 2; ++kk)
          acc[qm * MF + i][qn * 2 + n] = __builtin_amdgcn_mfma_f32_16x16x32_bf16(
              af[i * 2 + kk], bq[n * 2 + kk], acc[qm * MF + i][qn * 2 + n], 0, 0, 0);
  };
  auto MID = [&] {
    SB0;
    __builtin_amdgcn_s_barrier();
    LGKM0;
    SB0;
    __builtin_amdgcn_s_setprio(1);
  };
  auto END = [&] {
    __builtin_amdgcn_s_setprio(0);
    SB0;
    __builtin_amdgcn_s_barrier();
  };

  stageB(0, 0, 0); stageA(0, 0, 0); stageB(0, 1, 0); stageA(0, 1, 0);
  stageB(1, 0, 1); stageA(1, 0, 1);
  if constexpr (BM == 256) WAITVM(4); else WAITVM(3);
  __builtin_amdgcn_s_barrier();

  for (int j = 0; j < nit; ++j) {
    const int ta = 2 * j;
    const bool nl = (j + 1 < nit);
    ldA(0, 0); ldB(0, 0, bq0);
    stageB(1, 1, ta + 1);
    MID(); domf(0, 0, bq0); END();
    ldB(0, 1, bq1);
    stageA(1, 1, ta + 1);
    MID(); domf(0, 1, bq1); END();
    ldA(0, 1);
    if (nl) stageB(0, 0, ta + 2);
    MID(); domf(1, 1, bq1); END();
    if (nl) stageA(0, 0, ta + 2);
    MID(); domf(1, 0, bq0);
    __builtin_amdgcn_s_setprio(0); SB0;
    if (nl) { if constexpr (BM == 256) WAITVM(4); else WAITVM(3); }
    else WAITVM(0);
    __builtin_amdgcn_s_barrier();
    ldA(1, 0); ldB(1, 0, bq0);
    if (nl) stageB(0, 1, ta + 2);
    MID(); domf(0, 0, bq0); END();
    ldB(1, 1, bq1);
    if (nl) stageA(0, 1, ta + 2);
    MID(); domf(0, 1, bq1); END();
    ldA(1, 1);
    if (nl) stageB(1, 0, ta + 3);
    MID(); domf(1, 1, bq1); END();
    if (nl) stageA(1, 0, ta + 3);
    MID(); domf(1, 0, bq0);
    __builtin_amdgcn_s_setprio(0); SB0;
    if (nl) { if constexpr (BM == 256) WAITVM(4); else WAITVM(3); }
    __builtin_amdgcn_s_barrier();
  }
}

// ---------------- GEMM1: proj = x_mod @ w1 + b1 ; qkv bf16 + gelu(mlp) bf16 ----------------
__global__ __launch_bounds__(512, 2) void gemm1_kernel(
    const unsigned short* __restrict__ xmod, const unsigned short* __restrict__ w1t,
    const float* __restrict__ b1, unsigned short* __restrict__ qkv,
    unsigned short* __restrict__ hbuf) {
  __shared__ __align__(16) char smem[131072];
  f32x4 acc[8][4];
  const f32x4 zero = {0.f, 0.f, 0.f, 0.f};
#pragma unroll
  for (int i = 0; i < 8; ++i)
#pragma unroll
    for (int j = 0; j < 4; ++j) acc[i][j] = zero;
  const int orig = blockIdx.x;
  const int xcd = orig & 7;
  const int wgid = (xcd < 4 ? xcd * 95 : 380 + (xcd - 4) * 94) + (orig >> 3);
  const int m0 = (wgid % 9) * 256;
  const int n0 = (wgid / 9) * 256;
  gemm8_core<256>(xmod, HID_D, w1t, HID_D, m0, n0, 24, smem, acc);
  const int lane = threadIdx.x & 63;
  const int g = lane >> 4, c = lane & 15;
  const int w = threadIdx.x >> 6;
  const int wm = (w >> 2) * 128, wn = (w & 3) * 64;
  const bool is_mlp = (n0 >= QKVN);
#pragma unroll
  for (int mf = 0; mf < 8; ++mf)
#pragma unroll
    for (int nf = 0; nf < 4; ++nf)
#pragma unroll
      for (int j = 0; j < 4; ++j) {
        const int row = m0 + wm + mf * 16 + g * 4 + j;
        const int col = n0 + wn + nf * 16 + c;
        const float v = acc[mf][nf][j] + b1[col];
        if (!is_mlp) {
          qkv[(size_t)row * QKVN + col] = f2bf(v);
        } else {
          hbuf[(size_t)row * K2_D + HID_D + (col - QKVN)] = f2bf(gelu_f(v));
        }
      }
}

// ---------------- GEMM2: out = x + (h @ w2 + b2) * gate ----------------
__global__ __launch_bounds__(512, 2) void gemm2_kernel(
    const unsigned short* __restrict__ hbuf, const unsigned short* __restrict__ w2t,
    const float* __restrict__ b2, const float* __restrict__ x,
    const float* __restrict__ mod, float* __restrict__ out) {
  __shared__ __align__(16) char smem[98304];
  f32x4 acc[4][4];
  const f32x4 zero = {0.f, 0.f, 0.f, 0.f};
#pragma unroll
  for (int i = 0; i < 4; ++i)
#pragma unroll
    for (int j = 0; j < 4; ++j) acc[i][j] = zero;
  const int orig = blockIdx.x;
  const int wgid = (orig & 7) * 27 + (orig >> 3);
  const int m0 = (wgid % 18) * 128;
  const int n0 = (wgid / 18) * 256;
  gemm8_core<128>(hbuf, K2_D, w2t, K2_D, m0, n0, 120, smem, acc);
  const int lane = threadIdx.x & 63;
  const int g = lane >> 4, c = lane & 15;
  const int w = threadIdx.x >> 6;
  const int wm = (w >> 2) * 64, wn = (w & 3) * 64;
#pragma unroll
  for (int mf = 0; mf < 4; ++mf)
#pragma unroll
    for (int nf = 0; nf < 4; ++nf)
#pragma unroll
      for (int j = 0; j < 4; ++j) {
        const int row = m0 + wm + mf * 16 + g * 4 + j;
        const int col = n0 + wn + nf * 16 + c;
        const float v = acc[mf][nf][j] + b2[col];
        out[(size_t)row * HID_D + col] =
            x[(size_t)row * HID_D + col] + v * mod[6144 + col];
      }
}

// ---------------- q/k rmsnorm + rope -> qr, kr [h][l][d] bf16 (q pre-scaled) ----------------
__global__ __launch_bounds__(256) void qk_norm_rope_kernel(
    const unsigned short* __restrict__ qkv, const float* __restrict__ qw,
    const float* __restrict__ kw, const float* __restrict__ fc,
    const float* __restrict__ fs, const int* __restrict__ img_len_p,
    unsigned short* __restrict__ qr, unsigned short* __restrict__ kr) {
  const int l = blockIdx.x;
  const int t = threadIdx.x;
  const int wv = t >> 6;
  const int lane = t & 63;
  const int img = *img_len_p;
  const bool do_rope = (l < img);
  float cc = 1.f, ss = 0.f;
  if (do_rope) {
    cc = fc[l * HD_D + 2 * lane];
    ss = fs[l * HD_D + 2 * lane];
  }
  const float qw0 = qw[2 * lane], qw1 = qw[2 * lane + 1];
  const float kw0 = kw[2 * lane], kw1 = kw[2 * lane + 1];
#pragma unroll
  for (int hh = 0; hh < 6; ++hh) {
    const int h = hh * 4 + wv;
    {
      unsigned int pq = *(const unsigned int*)&qkv[(size_t)l * QKVN + h * HD_D + 2 * lane];
      float q0 = bf2f((unsigned short)(pq & 0xffff));
      float q1 = bf2f((unsigned short)(pq >> 16));
      float sq = q0 * q0 + q1 * q1;
#pragma unroll
      for (int o = 1; o < 64; o <<= 1) sq += __shfl_xor(sq, o);
      const float r = rsqrtf(sq * (1.f / HD_D) + EPS_V);
      float a = q0 * r * qw0, b = q1 * r * qw1;
      float e = a, od = b;
      if (do_rope) { e = a * cc - b * ss; od = a * ss + b * cc; }
      e *= ATTN_SC; od *= ATTN_SC;
      unsigned int pk = (unsigned)f2bf(e) | ((unsigned)f2bf(od) << 16);
      *(unsigned int*)&qr[((size_t)h * L_SEQ + l) * HD_D + 2 * lane] = pk;
    }
    {
      unsigned int pkk = *(const unsigned int*)&qkv[(size_t)l * QKVN + HID_D + h * HD_D + 2 * lane];
      float k0 = bf2f((unsigned short)(pkk & 0xffff));
      float k1 = bf2f((unsigned short)(pkk >> 16));
      float sq = k0 * k0 + k1 * k1;
#pragma unroll
      for (int o = 1; o < 64; o <<= 1) sq += __shfl_xor(sq, o);
      const float r = rsqrtf(sq * (1.f / HD_D) + EPS_V);
      float a = k0 * r * kw0, b = k1 * r * kw1;
      float e = a, od = b;
      if (do_rope) { e = a * cc - b * ss; od = a * ss + b * cc; }
      unsigned int pk = (unsigned)f2bf(e) | ((unsigned)f2bf(od) << 16);
      *(unsigned int*)&kr[((size_t)h * L_SEQ + l) * HD_D + 2 * lane] = pk;
    }
  }
}

// ---------------- v transpose -> vT [h][d][l] bf16 ----------------
__global__ __launch_bounds__(256) void v_transpose_kernel(
    const unsigned short* __restrict__ qkv, unsigned short* __restrict__ vT) {
  __shared__ unsigned short lv[128 * 64];
  const int h = blockIdx.y;
  const int l0 = blockIdx.x * 64;
  const int t = threadIdx.x;
#pragma unroll
  for (int p = 0; p < 4; ++p) {
    const int idx = p * 256 + t;
    const int l = idx >> 4;
    const int d8 = (idx & 15) * 8;
    u16x8 v = *(const u16x8*)&qkv[(size_t)(l0 + l) * QKVN + 2 * HID_D + h * HD_D + d8];
#pragma unroll
    for (int e = 0; e < 8; ++e) {
      const int d = d8 + e;
      const unsigned sw = (unsigned)(((d >> 2) & 7) << 4);
      *(unsigned short*)((char*)lv + (((unsigned)d * 128 + 2 * l) ^ sw)) = v[e];
    }
  }
  __syncthreads();
  const int d = t >> 1;
  const int half = t & 1;
  const unsigned swr = (unsigned)(((d >> 2) & 7) << 4);
#pragma unroll
  for (int j2 = 0; j2 < 4; ++j2) {
    u32x4 v = *(const u32x4*)((const char*)lv + ((d * 128 + half * 64 + j2 * 16) ^ swr));
    *(u32x4*)&vT[(size_t)(h * HD_D + d) * L_SEQ + l0 + half * 32 + j2 * 8] = v;
  }
}

// ---- flash attention: 64 q-rows/block, double-buffered gload_lds K/V staging ----
// T3 minimal 2-phase: stage(buf^1, t+1) at loop top -> compute(buf) ->
// vmcnt(0) + ONE barrier per tile. LDS dest linear (wave-uniform+lane*16);
// read-side XOR swizzle pre-applied to per-lane GLOBAL source chunk (rule #21).
__global__ __launch_bounds__(256) void attn_kernel(
    const unsigned short* __restrict__ qr, const unsigned short* __restrict__ kr,
    const unsigned short* __restrict__ vT, unsigned short* __restrict__ hbuf) {
  __shared__ unsigned short lds_k[2][64 * 128];   // 2 x 16 KB
  __shared__ unsigned short lds_v[2][128 * 64];   // 2 x 16 KB
  __shared__ unsigned short lds_p[4 * 16 * 64];   // 8 KB
  const int hidx = blockIdx.y;
  const int l0 = blockIdx.x * 64;
  const int t = threadIdx.x;
  const int lane = t & 63;
  const int w = t >> 6;
  const int g = lane >> 4;
  const int c = lane & 15;

  // staging geometry (per wave: 4 K-instr x 4 rows, 4 V-instr x 8 rows)
  const int krow = w * 16 + (lane >> 4);                       // + i*4
  const int kcol_e = ((lane & 15) ^ ((lane >> 4) & 7)) * 8;    // i even
  const int kcol_o = ((lane & 15) ^ (((lane >> 4) + 4) & 7)) * 8;  // i odd
  const int vrow = w * 32 + (lane >> 3);                       // + i*8
  const int vcol = ((lane & 7) ^ ((lane >> 3) & 7)) * 8;

  auto stage = [&](int buf, int kv0) {
#pragma unroll
    for (int i = 0; i < 4; ++i) {
      const int col = (i & 1) ? kcol_o : kcol_e;
      gload16(kr + ((size_t)hidx * L_SEQ + kv0 + krow + i * 4) * HD_D + col,
              (char*)lds_k + buf * 16384 + w * 4096 + i * 1024);
    }
#pragma unroll
    for (int i = 0; i < 4; ++i)
      gload16(vT + ((size_t)(hidx * HD_D) + vrow + i * 8) * L_SEQ + kv0 + vcol,
              (char*)lds_v + buf * 16384 + w * 4096 + i * 1024);
  };

  bf16x8 qa[4];
  {
    const unsigned short* qrow = qr + ((size_t)hidx * L_SEQ + l0 + w * 16 + c) * HD_D;
#pragma unroll
    for (int ks = 0; ks < 4; ++ks)
      qa[ks] = *(const bf16x8*)&qrow[ks * 32 + g * 8];
  }
  f32x4 acc[8];
  const f32x4 zero = {0.f, 0.f, 0.f, 0.f};
#pragma unroll
  for (int i = 0; i < 8; ++i) acc[i] = zero;
  float m_r[4] = {-1e30f, -1e30f, -1e30f, -1e30f};
  float l_r[4] = {0.f, 0.f, 0.f, 0.f};

  // prologue: tile 0 -> buf 0
  stage(0, 0);
  SB0; WAITVM(0);
  __builtin_amdgcn_s_barrier();

  int cur = 0;
  for (int kv0 = 0; kv0 < L_SEQ; kv0 += 64) {
    const bool nl = (kv0 + 64 < L_SEQ);
    if (nl) stage(cur ^ 1, kv0 + 64);   // flies under this tile's compute
    const char* bk = (const char*)lds_k + cur * 16384;
    const char* bv = (const char*)lds_v + cur * 16384;
    f32x4 s[4];
#pragma unroll
    for (int cf = 0; cf < 4; ++cf) s[cf] = zero;
#pragma unroll
    for (int ks = 0; ks < 4; ++ks) {
      const int kb = (ks * 32 + g * 8) * 2;
#pragma unroll
      for (int cf = 0; cf < 4; ++cf) {
        const int kvr = cf * 16 + c;
        bf16x8 kf = *(const bf16x8*)(bk + ((kvr * 256 + kb) ^ ((kvr & 7) << 4)));
        s[cf] = __builtin_amdgcn_mfma_f32_16x16x32_bf16(qa[ks], kf, s[cf], 0, 0, 0);
      }
    }
    float pv[4][4];
    float alpha[4];
#pragma unroll
    for (int r = 0; r < 4; ++r) {
      float mx = fmaxf(fmaxf(s[0][r], s[1][r]), fmaxf(s[2][r], s[3][r]));
      mx = fmaxf(mx, __shfl_xor(mx, 1));
      mx = fmaxf(mx, __shfl_xor(mx, 2));
      mx = fmaxf(mx, __shfl_xor(mx, 4));
      mx = fmaxf(mx, __shfl_xor(mx, 8));
      const float mnew = fmaxf(m_r[r], mx);
      alpha[r] = __expf(m_r[r] - mnew);
      float rsum = 0.f;
#pragma unroll
      for (int cf = 0; cf < 4; ++cf) {
        const float p_ = __expf(s[cf][r] - mnew);
        pv[cf][r] = p_;
        rsum += p_;
      }
      rsum += __shfl_xor(rsum, 1);
      rsum += __shfl_xor(rsum, 2);
      rsum += __shfl_xor(rsum, 4);
      rsum += __shfl_xor(rsum, 8);
      l_r[r] = l_r[r] * alpha[r] + rsum;
      m_r[r] = mnew;
    }
#pragma unroll
    for (int of = 0; of < 8; ++of)
#pragma unroll
      for (int r = 0; r < 4; ++r) acc[of][r] *= alpha[r];
#pragma unroll
    for (int cf = 0; cf < 4; ++cf)
#pragma unroll
      for (int r = 0; r < 4; ++r) {
        const int row = g * 4 + r;
        const int col = cf * 16 + c;
        *(unsigned short*)((char*)lds_p +
                           ((w * 2048 + row * 128 + col * 2) ^ ((row & 7) << 4))) =
            f2bf(pv[cf][r]);
      }
    LGKM0;
    SB0;
#pragma unroll
    for (int ks = 0; ks < 2; ++ks) {
      bf16x8 pa = *(const bf16x8*)((const char*)lds_p +
                                   ((w * 2048 + c * 128 + (ks * 32 + g * 8) * 2) ^
                                    ((c & 7) << 4)));
#pragma unroll
      for (int of = 0; of < 8; ++of) {
        const int dcol = of * 16 + c;
        bf16x8 vb = *(const bf16x8*)(bv + ((dcol * 128 + (ks * 32 + g * 8) * 2) ^
                                           ((dcol & 7) << 4)));
        acc[of] = __builtin_amdgcn_mfma_f32_16x16x32_bf16(pa, vb, acc[of], 0, 0, 0);
      }
    }
    if (nl) {
      SB0; WAITVM(0);                 // staged tile resident
      __builtin_amdgcn_s_barrier();   // all waves done reading buf[cur]
      cur ^= 1;
    }
  }
  float rinv[4];
#pragma unroll
  for (int r = 0; r < 4; ++r) rinv[r] = 1.f / l_r[r];
#pragma unroll
  for (int of = 0; of < 8; ++of)
#pragma unroll
    for (int r = 0; r < 4; ++r) {
      const int row = l0 + w * 16 + g * 4 + r;
      const int col = hidx * HD_D + of * 16 + c;
      hbuf[(size_t)row * K2_D + col] = f2bf(acc[of][r] * rinv[r]);
    }
}

extern "C" void kernel_launch(void* const* d_in, const int* in_sizes, int n_in,
                              void* d_out, int out_size, void* d_ws, size_t ws_size,
                              hipStream_t stream) {
  (void)in_sizes; (void)n_in; (void)out_size; (void)ws_size;
  const float* x = (const float*)d_in[0];
  const float* vec = (const float*)d_in[1];
  const int* img_len = (const int*)d_in[2];
  const float* fc = (const float*)d_in[3];
  const float* fs = (const float*)d_in[4];
  const float* mod_w = (const float*)d_in[5];
  const float* mod_b = (const float*)d_in[6];
  const float* w1 = (const float*)d_in[7];
  const float* b1 = (const float*)d_in[8];
  const float* qw = (const float*)d_in[9];
  const float* kw = (const float*)d_in[10];
  const float* w2 = (const float*)d_in[11];
  const float* b2 = (const float*)d_in[12];
  float* out = (float*)d_out;

  char* wsb = (char*)d_ws;
  float* mod = (float*)(wsb + 0);
  float* partial = (float*)(wsb + 36864);
  unsigned short* xmod = (unsigned short*)(wsb + 331776);
  unsigned short* qkv = (unsigned short*)(wsb + 14487552);   // bf16
  unsigned short* hbuf = (unsigned short*)(wsb + 99422208);
  unsigned short* qr = (unsigned short*)(wsb + 170201088);
  unsigned short* kr = (unsigned short*)(wsb + 184356864);
  unsigned short* vT = (unsigned short*)(wsb + 198512640);
  unsigned short* wt = (unsigned short*)(wsb + 212668416);

  mod_partial_kernel<<<dim3(36, 8), 256, 0, stream>>>(vec, mod_w, partial);
  mod_reduce_kernel<<<36, 256, 0, stream>>>(partial, mod_b, mod);
  ln_mod_kernel<<<2304, 256, 0, stream>>>(x, mod, xmod);
  convert_transpose_kernel<<<dim3(N1_D / 64, HID_D / 64), 256, 0, stream>>>(
      w1, wt, HID_D, N1_D);
  gemm1_kernel<<<756, 512, 0, stream>>>(xmod, wt, b1, qkv, hbuf);
  convert_transpose_kernel<<<dim3(HID_D / 64, K2_D / 64), 256, 0, stream>>>(
      w2, wt, K2_D, HID_D);
  qk_norm_rope_kernel<<<2304, 256, 0, stream>>>(qkv, qw, kw, fc, fs, img_len, qr, kr);
  v_transpose_kernel<<<dim3(36, 24), 256, 0, stream>>>(qkv, vT);
  attn_kernel<<<dim3(36, 24), 256, 0, stream>>>(qr, kr, vT, hbuf);
  gemm2_kernel<<<216, 512, 0, stream>>>(hbuf, wt, b2, x, mod, out);
}

// Round 15
// 932.864 us; speedup vs baseline: 1.0266x; 1.0266x over previous
//
#include <hip/hip_runtime.h>

#define L_SEQ 2304
#define HID_D 3072
#define NH_D 24
#define HD_D 128
#define N1_D 21504   // 3*HID + MLP
#define QKVN 9216    // 3*HID
#define K2_D 15360   // HID + MLP
#define EPS_V 1e-6f
#define ATTN_SC 0.08838834764831843f  // 1/sqrt(128)

typedef __bf16 bf16x8 __attribute__((ext_vector_type(8)));
typedef float f32x4 __attribute__((ext_vector_type(4)));
typedef unsigned int u32x4 __attribute__((ext_vector_type(4)));
typedef unsigned short u16x8 __attribute__((ext_vector_type(8)));
typedef unsigned short u16x4 __attribute__((ext_vector_type(4)));

#define WAITVM(N) asm volatile("s_waitcnt vmcnt(" #N ")" ::: "memory")
#define LGKM0 asm volatile("s_waitcnt lgkmcnt(0)" ::: "memory")
#define SB0 __builtin_amdgcn_sched_barrier(0)

__device__ __forceinline__ unsigned short f2bf(float f) {
  unsigned int u = __builtin_bit_cast(unsigned int, f);
  u += 0x7fffu + ((u >> 16) & 1u);   // round-to-nearest-even
  return (unsigned short)(u >> 16);
}

__device__ __forceinline__ float gelu_f(float x) {
  float u = 0.7978845608028654f * (x + 0.044715f * x * x * x);
  float e = __expf(2.f * u);
  float th = 1.f - 2.f / (e + 1.f);   // tanh(u), overflow-safe
  return 0.5f * x * (1.f + th);
}

// async global->LDS, 16B per lane; lds base must be wave-uniform
__device__ __forceinline__ void gload16(const void* g, void* l) {
  __builtin_amdgcn_global_load_lds(
      (const __attribute__((address_space(1))) unsigned int*)g,
      (__attribute__((address_space(3))) unsigned int*)l, 16, 0, 0);
}

// ---------------- mod = silu(vec) @ mod_w + mod_b ----------------
__global__ __launch_bounds__(256) void mod_partial_kernel(
    const float* __restrict__ vec, const float* __restrict__ mod_w,
    float* __restrict__ partial) {
  __shared__ float s[384];
  const int t = threadIdx.x;
  const int kb = blockIdx.y;
  const int k0 = kb * 384;
  for (int p = t; p < 384; p += 256) {
    float v = vec[k0 + p];
    s[p] = v / (1.f + __expf(-v));
  }
  __syncthreads();
  const int n = blockIdx.x * 256 + t;
  float acc = 0.f;
  const float* wp = mod_w + (size_t)k0 * QKVN + n;
#pragma unroll 4
  for (int j = 0; j < 384; ++j) acc += s[j] * wp[(size_t)j * QKVN];
  partial[kb * QKVN + n] = acc;
}

__global__ __launch_bounds__(256) void mod_reduce_kernel(
    const float* __restrict__ partial, const float* __restrict__ mod_b,
    float* __restrict__ mod) {
  const int n = blockIdx.x * 256 + threadIdx.x;
  float acc = mod_b[n];
#pragma unroll
  for (int i = 0; i < 8; ++i) acc += partial[i * QKVN + n];
  mod[n] = acc;
}

// ---------------- x_mod = LN(x)*(1+scale) + shift  (bf16) ----------------
__global__ __launch_bounds__(256) void ln_mod_kernel(
    const float* __restrict__ x, const float* __restrict__ mod,
    unsigned short* __restrict__ xmod) {
  const int row = blockIdx.x;
  const int t = threadIdx.x;
  const float* xr = x + (size_t)row * HID_D;
  float4 v[3];
  float sum = 0.f, sq = 0.f;
#pragma unroll
  for (int p = 0; p < 3; ++p) {
    v[p] = *(const float4*)&xr[p * 1024 + t * 4];
    sum += v[p].x + v[p].y + v[p].z + v[p].w;
    sq += v[p].x * v[p].x + v[p].y * v[p].y + v[p].z * v[p].z + v[p].w * v[p].w;
  }
#pragma unroll
  for (int o = 1; o < 64; o <<= 1) {
    sum += __shfl_xor(sum, o);
    sq += __shfl_xor(sq, o);
  }
  __shared__ float rs[8];
  const int w = t >> 6;
  if ((t & 63) == 0) { rs[w] = sum; rs[4 + w] = sq; }
  __syncthreads();
  sum = rs[0] + rs[1] + rs[2] + rs[3];
  sq = rs[4] + rs[5] + rs[6] + rs[7];
  const float mu = sum * (1.f / HID_D);
  const float var = sq * (1.f / HID_D) - mu * mu;
  const float rstd = rsqrtf(var + EPS_V);
#pragma unroll
  for (int p = 0; p < 3; ++p) {
    const int c = p * 1024 + t * 4;
    float4 sc = *(const float4*)&mod[3072 + c];
    float4 sh = *(const float4*)&mod[c];
    u16x4 o4;
    o4[0] = f2bf((v[p].x - mu) * rstd * (1.f + sc.x) + sh.x);
    o4[1] = f2bf((v[p].y - mu) * rstd * (1.f + sc.y) + sh.y);
    o4[2] = f2bf((v[p].z - mu) * rstd * (1.f + sc.z) + sh.z);
    o4[3] = f2bf((v[p].w - mu) * rstd * (1.f + sc.w) + sh.w);
    *(u16x4*)&xmod[(size_t)row * HID_D + c] = o4;
  }
}

// ---------------- convert+transpose: src f32 [K][N] -> dst bf16 [N][K] ----------------
__global__ __launch_bounds__(256) void convert_transpose_kernel(
    const float* __restrict__ src, unsigned short* __restrict__ dst,
    const int K, const int N) {
  __shared__ unsigned short lt[64][72];
  const int t = threadIdx.x;
  const int n0 = blockIdx.x * 64;
  const int k0 = blockIdx.y * 64;
  const int kr = t >> 4;
  const int n4 = (t & 15) * 4;
#pragma unroll
  for (int p = 0; p < 4; ++p) {
    const int k = kr + p * 16;
    float4 v = *(const float4*)&src[(size_t)(k0 + k) * N + n0 + n4];
    lt[n4 + 0][k] = f2bf(v.x);
    lt[n4 + 1][k] = f2bf(v.y);
    lt[n4 + 2][k] = f2bf(v.z);
    lt[n4 + 3][k] = f2bf(v.w);
  }
  __syncthreads();
  const int nr = t >> 2;
  const int kc = (t & 3) * 16;
  u16x8 a = *(const u16x8*)&lt[nr][kc];
  u16x8 b = *(const u16x8*)&lt[nr][kc + 8];
  unsigned short* dp = &dst[(size_t)(n0 + nr) * K + k0 + kc];
  *(u16x8*)dp = a;
  *(u16x8*)(dp + 8) = b;
}

// ======== 8-phase deep-pipelined GEMM core (R7, proven; both GEMMs) ========
template <int BM>
__device__ __forceinline__ void gemm8_core(
    const unsigned short* __restrict__ A, const int lda,
    const unsigned short* __restrict__ B, const int ldb,
    const int m0, const int n0, const int nit, char* lds, f32x4 (*acc)[4]) {
  constexpr int AREG = (BM == 256) ? 16384 : 8192;
  constexpr int ABUF = 2 * AREG;
  constexpr int BOFF = 2 * ABUF;
  constexpr int BREG = 16384;
  constexpr int BBUF = 32768;
  constexpr int AROWS = (BM == 256) ? 128 : 64;
  constexpr int AI = (BM == 256) ? 2 : 1;
  constexpr int MF = (BM == 256) ? 4 : 2;
  constexpr int QM = (BM == 256) ? 64 : 32;

  const int t = threadIdx.x;
  const int lane = t & 63;
  const int w = t >> 6;
  const int g = lane >> 4;
  const int c = lane & 15;
  const int sr8 = lane >> 3;
  const int scol = ((lane & 7) ^ sr8) * 8;
  const int arg = w >> 2;
  const int brg = (w & 3) >> 1;
  const int bbase = (w & 1) * 64;

  auto stageA = [&](int buf, int rg, int kt) {
#pragma unroll
    for (int i = 0; i < AI; ++i)
      gload16(A + (size_t)(m0 + rg * AROWS + i * 64 + w * 8 + sr8) * lda +
                  kt * 64 + scol,
              lds + buf * ABUF + rg * AREG + i * 8192 + w * 1024);
  };
  auto stageB = [&](int buf, int rg, int kt) {
#pragma unroll
    for (int i = 0; i < 2; ++i)
      gload16(B + (size_t)(n0 + rg * 128 + i * 64 + w * 8 + sr8) * ldb +
                  kt * 64 + scol,
              lds + BOFF + buf * BBUF + rg * BREG + i * 8192 + w * 1024);
  };

  bf16x8 af[2 * MF], bq0[4], bq1[4];
  auto ldA = [&](int buf, int qm) {
    const char* ab = lds + buf * ABUF + arg * AREG;
#pragma unroll
    for (int i = 0; i < MF; ++i) {
      const int lr = qm * QM + i * 16 + c;
#pragma unroll
      for (int kk = 0; kk < 2; ++kk)
        af[i * 2 + kk] =
            *(const bf16x8*)(ab + lr * 128 + (((kk * 4 + g) ^ (c & 7)) << 4));
    }
  };
  auto ldB = [&](int buf, int qn, bf16x8* bq) {
    const char* bb = lds + BOFF + buf * BBUF + brg * BREG;
#pragma unroll
    for (int i = 0; i < 2; ++i) {
      const int lr = bbase + qn * 32 + i * 16 + c;
#pragma unroll
      for (int kk = 0; kk < 2; ++kk)
        bq[i * 2 + kk] =
            *(const bf16x8*)(bb + lr * 128 + (((kk * 4 + g) ^ (c & 7)) << 4));
    }
  };
  auto domf = [&](int qm, int qn, const bf16x8* bq) {
#pragma unroll
    for (int i = 0; i < MF; ++i)
#pragma unroll
      for (int n = 0; n < 2; ++n)
#pragma unroll
        for (int kk = 0; kk < 2; ++kk)
          acc[qm * MF + i][qn * 2 + n] = __builtin_amdgcn_mfma_f32_16x16x32_bf16(
              af[i * 2 + kk], bq[n * 2 + kk], acc[qm * MF + i][qn * 2 + n], 0, 0, 0);
  };
  auto MID = [&] {
    SB0;
    __builtin_amdgcn_s_barrier();
    LGKM0;
    SB0;
    __builtin_amdgcn_s_setprio(1);
  };
  auto END = [&] {
    __builtin_amdgcn_s_setprio(0);
    SB0;
    __builtin_amdgcn_s_barrier();
  };

  stageB(0, 0, 0); stageA(0, 0, 0); stageB(0, 1, 0); stageA(0, 1, 0);
  stageB(1, 0, 1); stageA(1, 0, 1);
  if constexpr (BM == 256) WAITVM(4); else WAITVM(3);
  __builtin_amdgcn_s_barrier();

  for (int j = 0; j < nit; ++j) {
    const int ta = 2 * j;
    const bool nl = (j + 1 < nit);
    ldA(0, 0); ldB(0, 0, bq0);
    stageB(1, 1, ta + 1);
    MID(); domf(0, 0, bq0); END();
    ldB(0, 1, bq1);
    stageA(1, 1, ta + 1);
    MID(); domf(0, 1, bq1); END();
    ldA(0, 1);
    if (nl) stageB(0, 0, ta + 2);
    MID(); domf(1, 1, bq1); END();
    if (nl) stageA(0, 0, ta + 2);
    MID(); domf(1, 0, bq0);
    __builtin_amdgcn_s_setprio(0); SB0;
    if (nl) { if constexpr (BM == 256) WAITVM(4); else WAITVM(3); }
    else WAITVM(0);
    __builtin_amdgcn_s_barrier();
    ldA(1, 0); ldB(1, 0, bq0);
    if (nl) stageB(0, 1, ta + 2);
    MID(); domf(0, 0, bq0); END();
    ldB(1, 1, bq1);
    if (nl) stageA(0, 1, ta + 2);
    MID(); domf(0, 1, bq1); END();
    ldA(1, 1);
    if (nl) stageB(1, 0, ta + 3);
    MID(); domf(1, 1, bq1); END();
    if (nl) stageA(1, 0, ta + 3);
    MID(); domf(1, 0, bq0);
    __builtin_amdgcn_s_setprio(0); SB0;
    if (nl) { if constexpr (BM == 256) WAITVM(4); else WAITVM(3); }
    __builtin_amdgcn_s_barrier();
  }
}

// ---------------- GEMM1: proj = x_mod @ w1 + b1 ; qkv f32 + gelu(mlp) bf16 ----------------
__global__ __launch_bounds__(512, 2) void gemm1_kernel(
    const unsigned short* __restrict__ xmod, const unsigned short* __restrict__ w1t,
    const float* __restrict__ b1, float* __restrict__ qkv,
    unsigned short* __restrict__ hbuf) {
  __shared__ __align__(16) char smem[131072];
  f32x4 acc[8][4];
  const f32x4 zero = {0.f, 0.f, 0.f, 0.f};
#pragma unroll
  for (int i = 0; i < 8; ++i)
#pragma unroll
    for (int j = 0; j < 4; ++j) acc[i][j] = zero;
  const int orig = blockIdx.x;
  const int xcd = orig & 7;
  const int wgid = (xcd < 4 ? xcd * 95 : 380 + (xcd - 4) * 94) + (orig >> 3);
  const int m0 = (wgid % 9) * 256;
  const int n0 = (wgid / 9) * 256;
  gemm8_core<256>(xmod, HID_D, w1t, HID_D, m0, n0, 24, smem, acc);
  const int lane = threadIdx.x & 63;
  const int g = lane >> 4, c = lane & 15;
  const int w = threadIdx.x >> 6;
  const int wm = (w >> 2) * 128, wn = (w & 3) * 64;
  const bool is_mlp = (n0 >= QKVN);
#pragma unroll
  for (int mf = 0; mf < 8; ++mf)
#pragma unroll
    for (int nf = 0; nf < 4; ++nf)
#pragma unroll
      for (int j = 0; j < 4; ++j) {
        const int row = m0 + wm + mf * 16 + g * 4 + j;
        const int col = n0 + wn + nf * 16 + c;
        const float v = acc[mf][nf][j] + b1[col];
        if (!is_mlp) {
          qkv[(size_t)row * QKVN + col] = v;
        } else {
          hbuf[(size_t)row * K2_D + HID_D + (col - QKVN)] = f2bf(gelu_f(v));
        }
      }
}

// ---------------- GEMM2: out = x + (h @ w2 + b2) * gate ----------------
__global__ __launch_bounds__(512, 2) void gemm2_kernel(
    const unsigned short* __restrict__ hbuf, const unsigned short* __restrict__ w2t,
    const float* __restrict__ b2, const float* __restrict__ x,
    const float* __restrict__ mod, float* __restrict__ out) {
  __shared__ __align__(16) char smem[98304];
  f32x4 acc[4][4];
  const f32x4 zero = {0.f, 0.f, 0.f, 0.f};
#pragma unroll
  for (int i = 0; i < 4; ++i)
#pragma unroll
    for (int j = 0; j < 4; ++j) acc[i][j] = zero;
  const int orig = blockIdx.x;
  const int wgid = (orig & 7) * 27 + (orig >> 3);
  const int m0 = (wgid % 18) * 128;
  const int n0 = (wgid / 18) * 256;
  gemm8_core<128>(hbuf, K2_D, w2t, K2_D, m0, n0, 120, smem, acc);
  const int lane = threadIdx.x & 63;
  const int g = lane >> 4, c = lane & 15;
  const int w = threadIdx.x >> 6;
  const int wm = (w >> 2) * 64, wn = (w & 3) * 64;
#pragma unroll
  for (int mf = 0; mf < 4; ++mf)
#pragma unroll
    for (int nf = 0; nf < 4; ++nf)
#pragma unroll
      for (int j = 0; j < 4; ++j) {
        const int row = m0 + wm + mf * 16 + g * 4 + j;
        const int col = n0 + wn + nf * 16 + c;
        const float v = acc[mf][nf][j] + b2[col];
        out[(size_t)row * HID_D + col] =
            x[(size_t)row * HID_D + col] + v * mod[6144 + col];
      }
}

// ---------------- q/k rmsnorm + rope -> qr, kr [h][l][d] bf16 (q pre-scaled) ----------------
__global__ __launch_bounds__(256) void qk_norm_rope_kernel(
    const float* __restrict__ qkv, const float* __restrict__ qw,
    const float* __restrict__ kw, const float* __restrict__ fc,
    const float* __restrict__ fs, const int* __restrict__ img_len_p,
    unsigned short* __restrict__ qr, unsigned short* __restrict__ kr) {
  const int l = blockIdx.x;
  const int t = threadIdx.x;
  const int wv = t >> 6;
  const int lane = t & 63;
  const int img = *img_len_p;
  const bool do_rope = (l < img);
  float cc = 1.f, ss = 0.f;
  if (do_rope) {
    cc = fc[l * HD_D + 2 * lane];
    ss = fs[l * HD_D + 2 * lane];
  }
  const float qw0 = qw[2 * lane], qw1 = qw[2 * lane + 1];
  const float kw0 = kw[2 * lane], kw1 = kw[2 * lane + 1];
#pragma unroll
  for (int hh = 0; hh < 6; ++hh) {
    const int h = hh * 4 + wv;
    {
      float2 q2 = *(const float2*)&qkv[(size_t)l * QKVN + h * HD_D + 2 * lane];
      float sq = q2.x * q2.x + q2.y * q2.y;
#pragma unroll
      for (int o = 1; o < 64; o <<= 1) sq += __shfl_xor(sq, o);
      const float r = rsqrtf(sq * (1.f / HD_D) + EPS_V);
      float a = q2.x * r * qw0, b = q2.y * r * qw1;
      float e = a, od = b;
      if (do_rope) { e = a * cc - b * ss; od = a * ss + b * cc; }
      e *= ATTN_SC; od *= ATTN_SC;
      unsigned int pk = (unsigned)f2bf(e) | ((unsigned)f2bf(od) << 16);
      *(unsigned int*)&qr[((size_t)h * L_SEQ + l) * HD_D + 2 * lane] = pk;
    }
    {
      float2 k2 = *(const float2*)&qkv[(size_t)l * QKVN + HID_D + h * HD_D + 2 * lane];
      float sq = k2.x * k2.x + k2.y * k2.y;
#pragma unroll
      for (int o = 1; o < 64; o <<= 1) sq += __shfl_xor(sq, o);
      const float r = rsqrtf(sq * (1.f / HD_D) + EPS_V);
      float a = k2.x * r * kw0, b = k2.y * r * kw1;
      float e = a, od = b;
      if (do_rope) { e = a * cc - b * ss; od = a * ss + b * cc; }
      unsigned int pk = (unsigned)f2bf(e) | ((unsigned)f2bf(od) << 16);
      *(unsigned int*)&kr[((size_t)h * L_SEQ + l) * HD_D + 2 * lane] = pk;
    }
  }
}

// ---------------- v transpose -> vT [h][d][l] bf16 ----------------
__global__ __launch_bounds__(256) void v_transpose_kernel(
    const float* __restrict__ qkv, unsigned short* __restrict__ vT) {
  __shared__ unsigned short lv[128 * 64];
  const int h = blockIdx.y;
  const int l0 = blockIdx.x * 64;
  const int t = threadIdx.x;
#pragma unroll
  for (int p = 0; p < 8; ++p) {
    const int idx = p * 256 + t;
    const int l = idx >> 5;
    const int d4 = (idx & 31) * 4;
    float4 v = *(const float4*)&qkv[(size_t)(l0 + l) * QKVN + 2 * HID_D + h * HD_D + d4];
    const unsigned sw = (unsigned)(((d4 >> 2) & 7) << 4);
    *(unsigned short*)((char*)lv + (((d4 + 0) * 128 + 2 * l) ^ sw)) = f2bf(v.x);
    *(unsigned short*)((char*)lv + (((d4 + 1) * 128 + 2 * l) ^ sw)) = f2bf(v.y);
    *(unsigned short*)((char*)lv + (((d4 + 2) * 128 + 2 * l) ^ sw)) = f2bf(v.z);
    *(unsigned short*)((char*)lv + (((d4 + 3) * 128 + 2 * l) ^ sw)) = f2bf(v.w);
  }
  __syncthreads();
  const int d = t >> 1;
  const int half = t & 1;
  const unsigned swr = (unsigned)(((d >> 2) & 7) << 4);
#pragma unroll
  for (int j2 = 0; j2 < 4; ++j2) {
    u32x4 v = *(const u32x4*)((const char*)lv + ((d * 128 + half * 64 + j2 * 16) ^ swr));
    *(u32x4*)&vT[(size_t)(h * HD_D + d) * L_SEQ + l0 + half * 32 + j2 * 8] = v;
  }
}

// ---------------- flash attention: per (head, 64 q rows) — R7-proven ----------------
__global__ __launch_bounds__(256) void attn_kernel(
    const unsigned short* __restrict__ qr, const unsigned short* __restrict__ kr,
    const unsigned short* __restrict__ vT, unsigned short* __restrict__ hbuf) {
  __shared__ unsigned short lds_k[64 * 128];
  __shared__ unsigned short lds_v[128 * 64];
  __shared__ unsigned short lds_p[4 * 16 * 64];
  const int hidx = blockIdx.y;
  const int l0 = blockIdx.x * 64;
  const int t = threadIdx.x;
  const int lane = t & 63;
  const int w = t >> 6;
  const int g = lane >> 4;
  const int c = lane & 15;

  bf16x8 qa[4];
  {
    const unsigned short* qrow = qr + ((size_t)hidx * L_SEQ + l0 + w * 16 + c) * HD_D;
#pragma unroll
    for (int ks = 0; ks < 4; ++ks)
      qa[ks] = *(const bf16x8*)&qrow[ks * 32 + g * 8];
  }
  f32x4 acc[8];
  const f32x4 zero = {0.f, 0.f, 0.f, 0.f};
#pragma unroll
  for (int i = 0; i < 8; ++i) acc[i] = zero;
  float m_r[4] = {-1e30f, -1e30f, -1e30f, -1e30f};
  float l_r[4] = {0.f, 0.f, 0.f, 0.f};

  for (int kv0 = 0; kv0 < L_SEQ; kv0 += 64) {
    __syncthreads();
#pragma unroll
    for (int p = 0; p < 4; ++p) {
      const int idx = p * 256 + t;
      const int r = idx >> 4, ch = idx & 15;
      u32x4 v = *(const u32x4*)&kr[((size_t)hidx * L_SEQ + kv0 + r) * HD_D + ch * 8];
      *(u32x4*)((char*)lds_k + ((r * 256 + ch * 16) ^ ((r & 7) << 4))) = v;
    }
#pragma unroll
    for (int p = 0; p < 4; ++p) {
      const int idx = p * 256 + t;
      const int d_ = idx >> 3, ch = idx & 7;
      u32x4 v = *(const u32x4*)&vT[(size_t)(hidx * HD_D + d_) * L_SEQ + kv0 + ch * 8];
      *(u32x4*)((char*)lds_v + ((d_ * 128 + ch * 16) ^ ((d_ & 7) << 4))) = v;
    }
    __syncthreads();
    f32x4 s[4];
#pragma unroll
    for (int cf = 0; cf < 4; ++cf) s[cf] = zero;
#pragma unroll
    for (int ks = 0; ks < 4; ++ks) {
      const int kb = (ks * 32 + g * 8) * 2;
#pragma unroll
      for (int cf = 0; cf < 4; ++cf) {
        const int kvr = cf * 16 + c;
        bf16x8 kf = *(const bf16x8*)((const char*)lds_k + ((kvr * 256 + kb) ^ ((kvr & 7) << 4)));
        s[cf] = __builtin_amdgcn_mfma_f32_16x16x32_bf16(qa[ks], kf, s[cf], 0, 0, 0);
      }
    }
    float pv[4][4];
    float alpha[4];
#pragma unroll
    for (int r = 0; r < 4; ++r) {
      float mx = fmaxf(fmaxf(s[0][r], s[1][r]), fmaxf(s[2][r], s[3][r]));
      mx = fmaxf(mx, __shfl_xor(mx, 1));
      mx = fmaxf(mx, __shfl_xor(mx, 2));
      mx = fmaxf(mx, __shfl_xor(mx, 4));
      mx = fmaxf(mx, __shfl_xor(mx, 8));
      const float mnew = fmaxf(m_r[r], mx);
      alpha[r] = __expf(m_r[r] - mnew);
      float rsum = 0.f;
#pragma unroll
      for (int cf = 0; cf < 4; ++cf) {
        const float p_ = __expf(s[cf][r] - mnew);
        pv[cf][r] = p_;
        rsum += p_;
      }
      rsum += __shfl_xor(rsum, 1);
      rsum += __shfl_xor(rsum, 2);
      rsum += __shfl_xor(rsum, 4);
      rsum += __shfl_xor(rsum, 8);
      l_r[r] = l_r[r] * alpha[r] + rsum;
      m_r[r] = mnew;
    }
#pragma unroll
    for (int of = 0; of < 8; ++of)
#pragma unroll
      for (int r = 0; r < 4; ++r) acc[of][r] *= alpha[r];
#pragma unroll
    for (int cf = 0; cf < 4; ++cf)
#pragma unroll
      for (int r = 0; r < 4; ++r) {
        const int row = g * 4 + r;
        const int col = cf * 16 + c;
        *(unsigned short*)((char*)lds_p +
                           ((w * 2048 + row * 128 + col * 2) ^ ((row & 7) << 4))) =
            f2bf(pv[cf][r]);
      }
    asm volatile("s_waitcnt lgkmcnt(0)" ::: "memory");
    __builtin_amdgcn_sched_barrier(0);
#pragma unroll
    for (int ks = 0; ks < 2; ++ks) {
      bf16x8 pa = *(const bf16x8*)((const char*)lds_p +
                                   ((w * 2048 + c * 128 + (ks * 32 + g * 8) * 2) ^
                                    ((c & 7) << 4)));
#pragma unroll
      for (int of = 0; of < 8; ++of) {
        const int dcol = of * 16 + c;
        bf16x8 vb = *(const bf16x8*)((const char*)lds_v +
                                     ((dcol * 128 + (ks * 32 + g * 8) * 2) ^
                                      ((dcol & 7) << 4)));
        acc[of] = __builtin_amdgcn_mfma_f32_16x16x32_bf16(pa, vb, acc[of], 0, 0, 0);
      }
    }
  }
  float rinv[4];
#pragma unroll
  for (int r = 0; r < 4; ++r) rinv[r] = 1.f / l_r[r];
#pragma unroll
  for (int of = 0; of < 8; ++of)
#pragma unroll
    for (int r = 0; r < 4; ++r) {
      const int row = l0 + w * 16 + g * 4 + r;
      const int col = hidx * HD_D + of * 16 + c;
      hbuf[(size_t)row * K2_D + col] = f2bf(acc[of][r] * rinv[r]);
    }
}

extern "C" void kernel_launch(void* const* d_in, const int* in_sizes, int n_in,
                              void* d_out, int out_size, void* d_ws, size_t ws_size,
                              hipStream_t stream) {
  (void)in_sizes; (void)n_in; (void)out_size; (void)ws_size;
  const float* x = (const float*)d_in[0];
  const float* vec = (const float*)d_in[1];
  const int* img_len = (const int*)d_in[2];
  const float* fc = (const float*)d_in[3];
  const float* fs = (const float*)d_in[4];
  const float* mod_w = (const float*)d_in[5];
  const float* mod_b = (const float*)d_in[6];
  const float* w1 = (const float*)d_in[7];
  const float* b1 = (const float*)d_in[8];
  const float* qw = (const float*)d_in[9];
  const float* kw = (const float*)d_in[10];
  const float* w2 = (const float*)d_in[11];
  const float* b2 = (const float*)d_in[12];
  float* out = (float*)d_out;

  char* wsb = (char*)d_ws;
  float* mod = (float*)(wsb + 0);
  float* partial = (float*)(wsb + 36864);
  unsigned short* xmod = (unsigned short*)(wsb + 331776);
  float* qkv = (float*)(wsb + 14487552);
  unsigned short* hbuf = (unsigned short*)(wsb + 99422208);
  unsigned short* qr = (unsigned short*)(wsb + 170201088);
  unsigned short* kr = (unsigned short*)(wsb + 184356864);
  unsigned short* vT = (unsigned short*)(wsb + 198512640);
  unsigned short* wt = (unsigned short*)(wsb + 212668416);

  mod_partial_kernel<<<dim3(36, 8), 256, 0, stream>>>(vec, mod_w, partial);
  mod_reduce_kernel<<<36, 256, 0, stream>>>(partial, mod_b, mod);
  ln_mod_kernel<<<2304, 256, 0, stream>>>(x, mod, xmod);
  convert_transpose_kernel<<<dim3(N1_D / 64, HID_D / 64), 256, 0, stream>>>(
      w1, wt, HID_D, N1_D);
  gemm1_kernel<<<756, 512, 0, stream>>>(xmod, wt, b1, qkv, hbuf);
  convert_transpose_kernel<<<dim3(HID_D / 64, K2_D / 64), 256, 0, stream>>>(
      w2, wt, K2_D, HID_D);
  qk_norm_rope_kernel<<<2304, 256, 0, stream>>>(qkv, qw, kw, fc, fs, img_len, qr, kr);
  v_transpose_kernel<<<dim3(36, 24), 256, 0, stream>>>(qkv, vT);
  attn_kernel<<<dim3(36, 24), 256, 0, stream>>>(qr, kr, vT, hbuf);
  gemm2_kernel<<<216, 512, 0, stream>>>(hbuf, wt, b2, x, mod, out);
}